// Round 7
// baseline (463.383 us; speedup 1.0000x reference)
//
#include <hip/hip_runtime.h>
#include <stdint.h>

// MetaMixer B=2 L=4096 H=1024 I=2048 K=4 G=8 ; M = B*L = 8192 tokens.
// GEMM1: p = hs @ in_proj_w^T (N=4096,K=1024) -> hpad / silu->gate
// CONV : im2col GEMM (N=2048,K=1024) epi (+conv_b)*gate -> xres
// LN   : layernorm(xres) -> hn
// GEMM2: silu(hn @ fc_w^T + fc_b)          (N=1024,K=2048)
// GEMM3: t @ cproj_w^T + cproj_b + xres    (N=2048,K=1024)
// GEMM4: h2 @ out_w^T (fp32 store)         (N=1024,K=2048)

#define TOKENS 8192
#define HDIM   1024
#define IDIM   2048
#define PADL   4099   // 4096 + 3 zero pad rows (causal K-1=3)

typedef __bf16 bf16_t;
typedef __bf16 bf16x8 __attribute__((ext_vector_type(8)));
typedef __bf16 bf16x4 __attribute__((ext_vector_type(4)));
typedef float  f32x4  __attribute__((ext_vector_type(4)));

__device__ __forceinline__ float silu_f(float v) { return v / (1.f + __expf(-v)); }

// ---------------- prep ----------------
__global__ __launch_bounds__(256) void cvt_f32_bf16(const float* __restrict__ in,
                                                    bf16_t* __restrict__ out, int n4) {
  int i = blockIdx.x * 256 + threadIdx.x;
  if (i < n4) {
    float4 v = reinterpret_cast<const float4*>(in)[i];
    bf16x4 o = {(bf16_t)v.x, (bf16_t)v.y, (bf16_t)v.z, (bf16_t)v.w};
    reinterpret_cast<bf16x4*>(out)[i] = o;
  }
}

// fused weight conversions (ranges in float4 units)
__global__ __launch_bounds__(256) void cvt_weights(
    const float* __restrict__ ipf, const float* __restrict__ fcf,
    const float* __restrict__ cpf, const float* __restrict__ outf,
    bf16_t* __restrict__ ipb, bf16_t* __restrict__ fcb,
    bf16_t* __restrict__ cpb, bf16_t* __restrict__ outb) {
  int i = blockIdx.x * 256 + threadIdx.x;
  const float* src; bf16_t* dst; int off;
  if (i < 1048576)      { src = ipf;  dst = ipb;  off = i; }
  else if (i < 1572864) { src = fcf;  dst = fcb;  off = i - 1048576; }
  else if (i < 2097152) { src = cpf;  dst = cpb;  off = i - 1572864; }
  else                  { src = outf; dst = outb; off = i - 2097152; }
  float4 v = reinterpret_cast<const float4*>(src)[off];
  bf16x4 o = {(bf16_t)v.x, (bf16_t)v.y, (bf16_t)v.z, (bf16_t)v.w};
  reinterpret_cast<bf16x4*>(dst)[off] = o;
}

// W2[o][k*256+ci] = conv_w[o][ci][k]
__global__ __launch_bounds__(256) void expand_convw(const float* __restrict__ cw,
                                                    bf16_t* __restrict__ w2) {
  int idx = blockIdx.x * 256 + threadIdx.x;
  int o = idx >> 10, r = idx & 1023, k = r >> 8, ci = r & 255;
  w2[idx] = (bf16_t)cw[(o << 10) + (ci << 2) + k];
}

__global__ __launch_bounds__(256) void zero_pad_rows(bf16_t* __restrict__ hpad) {
  int idx = blockIdx.x * 256 + threadIdx.x;
  if (idx < 2 * 3 * IDIM) {
    int b = idx / (3 * IDIM);
    int r = idx - b * (3 * IDIM);
    hpad[(size_t)b * PADL * IDIM + r] = (bf16_t)0.f;
  }
}

// ---------------- layernorm ----------------
__global__ __launch_bounds__(256) void ln_k(const bf16_t* __restrict__ x,
                                            const float* __restrict__ g,
                                            const float* __restrict__ b,
                                            bf16_t* __restrict__ out) {
  int row = blockIdx.x, tid = threadIdx.x;
  const bf16_t* xr = x + (size_t)row * IDIM;
  bf16x8 v = *reinterpret_cast<const bf16x8*>(xr + tid * 8);
  float f[8], s = 0.f, ss = 0.f;
#pragma unroll
  for (int j = 0; j < 8; ++j) { f[j] = (float)v[j]; s += f[j]; ss += f[j] * f[j]; }
#pragma unroll
  for (int o = 32; o; o >>= 1) { s += __shfl_xor(s, o); ss += __shfl_xor(ss, o); }
  __shared__ float red[2][4];
  int wv = tid >> 6, lane = tid & 63;
  if (lane == 0) { red[0][wv] = s; red[1][wv] = ss; }
  __syncthreads();
  s  = red[0][0] + red[0][1] + red[0][2] + red[0][3];
  ss = red[1][0] + red[1][1] + red[1][2] + red[1][3];
  float mean = s * (1.f / IDIM);
  float var  = ss * (1.f / IDIM) - mean * mean;
  float rstd = rsqrtf(var + 1e-5f);
  bf16x8 o8;
#pragma unroll
  for (int j = 0; j < 8; ++j) {
    int c = tid * 8 + j;
    o8[j] = (bf16_t)((f[j] - mean) * rstd * g[c] + b[c]);
  }
  *reinterpret_cast<bf16x8*>(out + (size_t)row * IDIM + tid * 8) = o8;
}

// ---------------- GEMM: deep-prefetch 4-phase pipeline ----------------
// C[M,N] = A[M,K] @ W[N,K]^T. BK=64, double-buffered LDS, T2 XOR-swizzle.
// ALL t+1 stage issues at ph0 of tile t; single vmcnt(0) at end of ph3
// (wait-depth ~3.5 phases >> HBM latency). setprio around MFMA clusters.
#define BARR __builtin_amdgcn_s_barrier()

template <int KIND, int N, int K, int BM, int BN, int WM, int WN>
__global__ __launch_bounds__(WM * WN * 64, 2) void gemm_k(
    const bf16_t* __restrict__ A, const bf16_t* __restrict__ W,
    const float* __restrict__ bias, const bf16_t* __restrict__ extra,
    void* __restrict__ outp, bf16_t* __restrict__ hpad_out,
    bf16_t* __restrict__ gate_out) {
  constexpr int NWAVE = WM * WN;
  constexpr int TM = BM / WM, TN = BN / WN;       // per-wave tile
  constexpr int MR = TM / 16, NR = TN / 16;       // fragment repeats
  constexpr int NT = K / 64;                      // K-tiles
  constexpr int NTN = N / BN;
  constexpr int SA = BM / (NWAVE * 8);            // stageA calls per tile
  constexpr int SB = BN / (NWAVE * 8);            // stageB calls per tile
  __shared__ bf16_t As[2][BM][64];
  __shared__ bf16_t Bs[2][BN][64];
  const int tid = threadIdx.x, lane = tid & 63, wid = tid >> 6;
  const int wr = wid / WN, wc = wid % WN;
  int bid = blockIdx.x;
  { const int cpx = gridDim.x >> 3; bid = (bid & 7) * cpx + (bid >> 3); }
  const int t0 = (bid / NTN) * BM, n0 = (bid % NTN) * BN;

  // swizzle (both sides): element at LDS (row, cb) is global col-byte cb ^ ((row&7)<<4)
  const int sw16 = (((lane & 7) ^ (lane >> 3)) << 4);  // stage-side source perm

  int cur = 0;

  // flat mapping: call j stages rows [j*NWAVE*8 + wid*8 + lane>>3]
  auto stageA = [&](int j, int tt) {
    const int row = j * NWAVE * 8 + wid * 8 + (lane >> 3);
    char* dst = (char*)&As[tt & 1][0][0] + row * 128 + ((lane & 7) << 4);
    const char* src;
    if constexpr (KIND == 1) {
      const int grow = t0 + row, b = grow >> 12, pos = grow & 4095;
      src = (const char*)A +
            (((size_t)b * PADL + pos + (tt >> 2)) * IDIM + (n0 & ~255) + ((tt & 3) << 6)) * 2 + sw16;
    } else {
      src = (const char*)A + ((size_t)(t0 + row) * K + tt * 64) * 2 + sw16;
    }
    __builtin_amdgcn_global_load_lds((const __attribute__((address_space(1))) void*)src,
                                     (__attribute__((address_space(3))) void*)dst, 16, 0, 0);
  };
  auto stageB = [&](int j, int tt) {
    const int row = j * NWAVE * 8 + wid * 8 + (lane >> 3);
    char* dst = (char*)&Bs[tt & 1][0][0] + row * 128 + ((lane & 7) << 4);
    const char* src = (const char*)W + ((size_t)(n0 + row) * K + tt * 64) * 2 + sw16;
    __builtin_amdgcn_global_load_lds((const __attribute__((address_space(1))) void*)src,
                                     (__attribute__((address_space(3))) void*)dst, 16, 0, 0);
  };
  auto stageAll = [&](int tt) {
#pragma unroll
    for (int j = 0; j < SA; ++j) stageA(j, tt);
#pragma unroll
    for (int j = 0; j < SB; ++j) stageB(j, tt);
  };
  auto readA = [&](int mi, int s) -> bf16x8 {
    const int row = wr * TM + mi * 16 + (lane & 15);
    const int cb = (s * 64 + ((lane >> 4) << 4)) ^ ((lane & 7) << 4);
    return *(const bf16x8*)((const char*)&As[cur][0][0] + row * 128 + cb);
  };
  auto readB = [&](int ni, int s) -> bf16x8 {
    const int row = wc * TN + ni * 16 + (lane & 15);
    const int cb = (s * 64 + ((lane >> 4) << 4)) ^ ((lane & 7) << 4);
    return *(const bf16x8*)((const char*)&Bs[cur][0][0] + row * 128 + cb);
  };

  f32x4 acc[MR][NR] = {};
  bf16x8 aF[MR / 2][2], bF[NR][2];

#define MMA_QUAD(MH, NH)                                                        \
  _Pragma("unroll") for (int mi = 0; mi < MR / 2; ++mi) {                       \
    _Pragma("unroll") for (int ni = 0; ni < NR / 2; ++ni) {                     \
      _Pragma("unroll") for (int s = 0; s < 2; ++s) {                           \
        acc[(MH) * (MR / 2) + mi][(NH) * (NR / 2) + ni] =                       \
            __builtin_amdgcn_mfma_f32_16x16x32_bf16(                            \
                aF[mi][s], bF[(NH) * (NR / 2) + ni][s],                         \
                acc[(MH) * (MR / 2) + mi][(NH) * (NR / 2) + ni], 0, 0, 0);      \
      }                                                                         \
    }                                                                           \
  }

  // prologue: stage tile 0, full drain
  stageAll(0);
  asm volatile("s_waitcnt vmcnt(0)");
  BARR;

  for (int t = 0; t < NT; ++t) {
    cur = t & 1;
    const bool nx = (t + 1) < NT;
    // ---- ph0: read aF-half0 + bF-half0; issue ALL t+1 stages ----
#pragma unroll
    for (int mi = 0; mi < MR / 2; ++mi)
#pragma unroll
      for (int s = 0; s < 2; ++s) aF[mi][s] = readA(mi, s);
#pragma unroll
    for (int ni = 0; ni < NR / 2; ++ni)
#pragma unroll
      for (int s = 0; s < 2; ++s) bF[ni][s] = readB(ni, s);
    if (nx) stageAll(t + 1);
    BARR;
    __builtin_amdgcn_s_setprio(1);
    MMA_QUAD(0, 0);
    __builtin_amdgcn_s_setprio(0);
    BARR;
    // ---- ph1: read bF-half1 ----
#pragma unroll
    for (int ni = 0; ni < NR / 2; ++ni)
#pragma unroll
      for (int s = 0; s < 2; ++s) bF[NR / 2 + ni][s] = readB(NR / 2 + ni, s);
    BARR;
    __builtin_amdgcn_s_setprio(1);
    MMA_QUAD(0, 1);
    __builtin_amdgcn_s_setprio(0);
    BARR;
    // ---- ph2: read aF-half1 ----
#pragma unroll
    for (int mi = 0; mi < MR / 2; ++mi)
#pragma unroll
      for (int s = 0; s < 2; ++s) aF[mi][s] = readA(MR / 2 + mi, s);
    BARR;
    __builtin_amdgcn_s_setprio(1);
    MMA_QUAD(1, 1);
    __builtin_amdgcn_s_setprio(0);
    BARR;
    // ---- ph3: MFMA immediately (no new reads); late drain of t+1 loads ----
    __builtin_amdgcn_s_setprio(1);
    MMA_QUAD(1, 0);
    __builtin_amdgcn_s_setprio(0);
    if (nx) asm volatile("s_waitcnt vmcnt(0)");
    BARR;
  }
#undef MMA_QUAD

  // epilogue: row = t0 + wr*TM + mi*16 + (lane>>4)*4 + r ; col = n0 + wc*TN + ni*16 + (lane&15)
#pragma unroll
  for (int mi = 0; mi < MR; ++mi) {
#pragma unroll
    for (int ni = 0; ni < NR; ++ni) {
      const int col = n0 + wc * TN + ni * 16 + (lane & 15);
      float bv = 0.f;
      if constexpr (KIND == 1 || KIND == 2 || KIND == 3) bv = bias[col];
#pragma unroll
      for (int r = 0; r < 4; ++r) {
        const int row = t0 + wr * TM + mi * 16 + ((lane >> 4) << 2) + r;
        float v = acc[mi][ni][r];
        if constexpr (KIND == 0) {
          if (n0 < IDIM) {
            int b = row >> 12, pos = row & 4095;
            hpad_out[((size_t)b * PADL + 3 + pos) * IDIM + col] = (bf16_t)v;
          } else {
            gate_out[(size_t)row * IDIM + (col - IDIM)] = (bf16_t)silu_f(v);
          }
        } else if constexpr (KIND == 1) {
          float gt = (float)extra[(size_t)row * IDIM + col];
          ((bf16_t*)outp)[(size_t)row * N + col] = (bf16_t)((v + bv) * gt);
        } else if constexpr (KIND == 2) {
          ((bf16_t*)outp)[(size_t)row * N + col] = (bf16_t)silu_f(v + bv);
        } else if constexpr (KIND == 3) {
          float res = (float)extra[(size_t)row * N + col];
          ((bf16_t*)outp)[(size_t)row * N + col] = (bf16_t)(v + bv + res);
        } else {
          ((float*)outp)[(size_t)row * N + col] = v;
        }
      }
    }
  }
}

// ---------------- launch ----------------
extern "C" void kernel_launch(void* const* d_in, const int* in_sizes, int n_in,
                              void* d_out, int out_size, void* d_ws, size_t ws_size,
                              hipStream_t stream) {
  const float* hs       = (const float*)d_in[0];
  const float* in_projw = (const float*)d_in[1];
  const float* conv_w   = (const float*)d_in[2];
  const float* conv_b   = (const float*)d_in[3];
  const float* ln_g     = (const float*)d_in[4];
  const float* ln_b     = (const float*)d_in[5];
  const float* fc_w     = (const float*)d_in[6];
  const float* fc_b     = (const float*)d_in[7];
  const float* cproj_w  = (const float*)d_in[8];
  const float* cproj_b  = (const float*)d_in[9];
  const float* out_w    = (const float*)d_in[10];

  char* ws = (char*)d_ws;
  size_t off = 0;
  auto alloc = [&](size_t bytes) {
    char* p = ws + off;
    off += (bytes + 255) & ~(size_t)255;
    return p;
  };
  bf16_t* hs_b  = (bf16_t*)alloc((size_t)TOKENS * HDIM * 2);
  bf16_t* w_ip  = (bf16_t*)alloc((size_t)2 * IDIM * HDIM * 2);
  bf16_t* w2c   = (bf16_t*)alloc((size_t)IDIM * 1024 * 2);
  bf16_t* w_fc  = (bf16_t*)alloc((size_t)HDIM * IDIM * 2);
  bf16_t* w_cp  = (bf16_t*)alloc((size_t)IDIM * HDIM * 2);
  bf16_t* w_out = (bf16_t*)alloc((size_t)HDIM * IDIM * 2);
  bf16_t* hpad  = (bf16_t*)alloc((size_t)2 * PADL * IDIM * 2);
  bf16_t* gate  = (bf16_t*)alloc((size_t)TOKENS * IDIM * 2);
  bf16_t* xres  = (bf16_t*)alloc((size_t)TOKENS * IDIM * 2);

  bf16_t* t_buf = hs_b;   // reuse
  bf16_t* hn    = gate;   // reuse
  bf16_t* h2    = hpad;   // reuse

  cvt_f32_bf16<<<8192, 256, 0, stream>>>(hs, hs_b, TOKENS * HDIM / 4);
  cvt_weights<<<10240, 256, 0, stream>>>(in_projw, fc_w, cproj_w, out_w,
                                         w_ip, w_fc, w_cp, w_out);
  expand_convw<<<8192, 256, 0, stream>>>(conv_w, w2c);
  zero_pad_rows<<<48, 256, 0, stream>>>(hpad);

  // GEMM1: 256^2 tiles, grid 32*16=512 (2 rounds)
  gemm_k<0, 4096, 1024, 256, 256, 2, 4><<<512, 512, 0, stream>>>(
      hs_b, w_ip, nullptr, nullptr, nullptr, hpad, gate);
  // CONV: grid 32*8=256 (1 round)
  gemm_k<1, 2048, 1024, 256, 256, 2, 4><<<256, 512, 0, stream>>>(
      hpad, w2c, conv_b, gate, xres, nullptr, nullptr);
  ln_k<<<TOKENS, 256, 0, stream>>>(xres, ln_g, ln_b, hn);
  // GEMM2: 256x128 tiles (N=1024), grid 32*8=256 (1 round)
  gemm_k<2, 1024, 2048, 256, 128, 2, 4><<<256, 512, 0, stream>>>(
      hn, w_fc, fc_b, nullptr, t_buf, nullptr, nullptr);
  // GEMM3: grid 256
  gemm_k<3, 2048, 1024, 256, 256, 2, 4><<<256, 512, 0, stream>>>(
      t_buf, w_cp, cproj_b, xres, h2, nullptr, nullptr);
  // GEMM4: 256x128 tiles, grid 256
  gemm_k<4, 1024, 2048, 256, 128, 2, 4><<<256, 512, 0, stream>>>(
      h2, w_out, nullptr, nullptr, d_out, nullptr, nullptr);
}

// Round 9
// 410.188 us; speedup vs baseline: 1.1297x; 1.1297x over previous
//
#include <hip/hip_runtime.h>
#include <stdint.h>

// MetaMixer B=2 L=4096 H=1024 I=2048 K=4 G=8 ; M = B*L = 8192 tokens.
// GEMM1: p = hs @ in_proj_w^T (N=4096,K=1024) -> hpad / silu->gate
// CONV : im2col GEMM (N=2048,K=1024) epi (+conv_b)*gate -> xres
// LN   : layernorm(xres) -> hn
// GEMM2: silu(hn @ fc_w^T + fc_b)          (N=1024,K=2048)
// GEMM3: t @ cproj_w^T + cproj_b + xres    (N=2048,K=1024)
// GEMM4: h2 @ out_w^T (fp32 store)         (N=1024,K=2048)

#define TOKENS 8192
#define HDIM   1024
#define IDIM   2048
#define PADL   4099   // 4096 + 3 zero pad rows (causal K-1=3)

typedef __bf16 bf16_t;
typedef __bf16 bf16x8 __attribute__((ext_vector_type(8)));
typedef __bf16 bf16x4 __attribute__((ext_vector_type(4)));
typedef float  f32x4  __attribute__((ext_vector_type(4)));

__device__ __forceinline__ float silu_f(float v) { return v / (1.f + __expf(-v)); }

// ---------------- prep ----------------
__global__ __launch_bounds__(256) void cvt_f32_bf16(const float* __restrict__ in,
                                                    bf16_t* __restrict__ out, int n4) {
  int i = blockIdx.x * 256 + threadIdx.x;
  if (i < n4) {
    float4 v = reinterpret_cast<const float4*>(in)[i];
    bf16x4 o = {(bf16_t)v.x, (bf16_t)v.y, (bf16_t)v.z, (bf16_t)v.w};
    reinterpret_cast<bf16x4*>(out)[i] = o;
  }
}

__global__ __launch_bounds__(256) void cvt_weights(
    const float* __restrict__ ipf, const float* __restrict__ fcf,
    const float* __restrict__ cpf, const float* __restrict__ outf,
    bf16_t* __restrict__ ipb, bf16_t* __restrict__ fcb,
    bf16_t* __restrict__ cpb, bf16_t* __restrict__ outb) {
  int i = blockIdx.x * 256 + threadIdx.x;
  const float* src; bf16_t* dst; int off;
  if (i < 1048576)      { src = ipf;  dst = ipb;  off = i; }
  else if (i < 1572864) { src = fcf;  dst = fcb;  off = i - 1048576; }
  else if (i < 2097152) { src = cpf;  dst = cpb;  off = i - 1572864; }
  else                  { src = outf; dst = outb; off = i - 2097152; }
  float4 v = reinterpret_cast<const float4*>(src)[off];
  bf16x4 o = {(bf16_t)v.x, (bf16_t)v.y, (bf16_t)v.z, (bf16_t)v.w};
  reinterpret_cast<bf16x4*>(dst)[off] = o;
}

// W2[o][k*256+ci] = conv_w[o][ci][k]
__global__ __launch_bounds__(256) void expand_convw(const float* __restrict__ cw,
                                                    bf16_t* __restrict__ w2) {
  int idx = blockIdx.x * 256 + threadIdx.x;
  int o = idx >> 10, r = idx & 1023, k = r >> 8, ci = r & 255;
  w2[idx] = (bf16_t)cw[(o << 10) + (ci << 2) + k];
}

__global__ __launch_bounds__(256) void zero_pad_rows(bf16_t* __restrict__ hpad) {
  int idx = blockIdx.x * 256 + threadIdx.x;
  if (idx < 2 * 3 * IDIM) {
    int b = idx / (3 * IDIM);
    int r = idx - b * (3 * IDIM);
    hpad[(size_t)b * PADL * IDIM + r] = (bf16_t)0.f;
  }
}

// ---------------- layernorm ----------------
__global__ __launch_bounds__(256) void ln_k(const bf16_t* __restrict__ x,
                                            const float* __restrict__ g,
                                            const float* __restrict__ b,
                                            bf16_t* __restrict__ out) {
  int row = blockIdx.x, tid = threadIdx.x;
  const bf16_t* xr = x + (size_t)row * IDIM;
  bf16x8 v = *reinterpret_cast<const bf16x8*>(xr + tid * 8);
  float f[8], s = 0.f, ss = 0.f;
#pragma unroll
  for (int j = 0; j < 8; ++j) { f[j] = (float)v[j]; s += f[j]; ss += f[j] * f[j]; }
#pragma unroll
  for (int o = 32; o; o >>= 1) { s += __shfl_xor(s, o); ss += __shfl_xor(ss, o); }
  __shared__ float red[2][4];
  int wv = tid >> 6, lane = tid & 63;
  if (lane == 0) { red[0][wv] = s; red[1][wv] = ss; }
  __syncthreads();
  s  = red[0][0] + red[0][1] + red[0][2] + red[0][3];
  ss = red[1][0] + red[1][1] + red[1][2] + red[1][3];
  float mean = s * (1.f / IDIM);
  float var  = ss * (1.f / IDIM) - mean * mean;
  float rstd = rsqrtf(var + 1e-5f);
  bf16x8 o8;
#pragma unroll
  for (int j = 0; j < 8; ++j) {
    int c = tid * 8 + j;
    o8[j] = (bf16_t)((f[j] - mean) * rstd * g[c] + b[c]);
  }
  *reinterpret_cast<bf16x8*>(out + (size_t)row * IDIM + tid * 8) = o8;
}

// ---------------- GEMM: 4-phase, deadline-ordered spread issue + counted vmcnt ----
// C[M,N] = A[M,K] @ W[N,K]^T. BK=64, dbuf LDS, T2 XOR-swizzle both-sides.
// Per tile t (staging t+1): ph0 issues A0,A1 ; ph1 B0,B1 ; ph2 B2,B3|A2 ;
// ph3 A2,A3|A3. Counted vmcnt(4)/(3) at phase ends (never 0 mid-loop) drains
// only loads >=2 phases old (~1400cy slack > ~900cy HBM latency).
#define BARR __builtin_amdgcn_s_barrier()

template <int N> __device__ __forceinline__ void vwait() {
  if constexpr (N == 0) asm volatile("s_waitcnt vmcnt(0)");
  else if constexpr (N == 2) asm volatile("s_waitcnt vmcnt(2)");
  else if constexpr (N == 3) asm volatile("s_waitcnt vmcnt(3)");
  else if constexpr (N == 4) asm volatile("s_waitcnt vmcnt(4)");
}

template <int KIND, int N, int K, int BM, int BN, int WM, int WN>
__global__ __launch_bounds__(WM * WN * 64, 2) void gemm_k(
    const bf16_t* __restrict__ A, const bf16_t* __restrict__ W,
    const float* __restrict__ bias, const bf16_t* __restrict__ extra,
    void* __restrict__ outp, bf16_t* __restrict__ hpad_out,
    bf16_t* __restrict__ gate_out) {
  constexpr int NWAVE = WM * WN;
  constexpr int TM = BM / WM, TN = BN / WN;       // per-wave tile
  constexpr int MR = TM / 16, NR = TN / 16;       // fragment repeats
  constexpr int NT = K / 64;                      // K-tiles
  constexpr int NTN = N / BN;
  constexpr int SA = BM / (NWAVE * 8);            // stageA calls per wave/tile
  constexpr int SB = BN / (NWAVE * 8);            // stageB calls per wave/tile
  static_assert(TM / SA == WN * 8, "A stage map");
  static_assert(TN / SB == WM * 8, "B stage map");
  static_assert(SA == 4 && (SB == 4 || SB == 2), "ledger assumes SA=4");
  __shared__ bf16_t As[2][BM][64];
  __shared__ bf16_t Bs[2][BN][64];
  const int tid = threadIdx.x, lane = tid & 63, wid = tid >> 6;
  const int wr = wid / WN, wc = wid % WN;
  int bid = blockIdx.x;
  { const int cpx = gridDim.x >> 3; bid = (bid & 7) * cpx + (bid >> 3); }
  const int t0 = (bid / NTN) * BM, n0 = (bid % NTN) * BN;

  // swizzle (both sides): LDS (row, cb) holds global col-byte cb ^ ((row&7)<<4)
  const int sw16 = (((lane & 7) ^ (lane >> 3)) << 4);  // stage-side source perm

  int cur = 0;

  // consumer-aligned stage maps: stageA(j) rows wr*TM + j*(TM/SA) + [0,TM/SA)
  // (read at ph0 for j<SA/2, ph2 for j>=SA/2); stageB(j) rows
  // wc*TN + j*(TN/SB) + [0,TN/SB) (ph0 for j<SB/2, ph1 for j>=SB/2).
  auto stageA = [&](int j, int tt) {
    const int row = wr * TM + j * (TM / SA) + (wc << 3) + (lane >> 3);
    char* dst = (char*)&As[tt & 1][0][0] + row * 128 + ((lane & 7) << 4);
    const char* src;
    if constexpr (KIND == 1) {
      const int grow = t0 + row, b = grow >> 12, pos = grow & 4095;
      src = (const char*)A +
            (((size_t)b * PADL + pos + (tt >> 2)) * IDIM + (n0 & ~255) + ((tt & 3) << 6)) * 2 + sw16;
    } else {
      src = (const char*)A + ((size_t)(t0 + row) * K + tt * 64) * 2 + sw16;
    }
    __builtin_amdgcn_global_load_lds((const __attribute__((address_space(1))) void*)src,
                                     (__attribute__((address_space(3))) void*)dst, 16, 0, 0);
  };
  auto stageB = [&](int j, int tt) {
    const int row = wc * TN + j * (TN / SB) + (wr << 3) + (lane >> 3);
    char* dst = (char*)&Bs[tt & 1][0][0] + row * 128 + ((lane & 7) << 4);
    const char* src = (const char*)W + ((size_t)(n0 + row) * K + tt * 64) * 2 + sw16;
    __builtin_amdgcn_global_load_lds((const __attribute__((address_space(1))) void*)src,
                                     (__attribute__((address_space(3))) void*)dst, 16, 0, 0);
  };
  auto readA = [&](int mi, int s) -> bf16x8 {
    const int row = wr * TM + mi * 16 + (lane & 15);
    const int cb = (s * 64 + ((lane >> 4) << 4)) ^ ((lane & 7) << 4);
    return *(const bf16x8*)((const char*)&As[cur][0][0] + row * 128 + cb);
  };
  auto readB = [&](int ni, int s) -> bf16x8 {
    const int row = wc * TN + ni * 16 + (lane & 15);
    const int cb = (s * 64 + ((lane >> 4) << 4)) ^ ((lane & 7) << 4);
    return *(const bf16x8*)((const char*)&Bs[cur][0][0] + row * 128 + cb);
  };

  f32x4 acc[MR][NR] = {};
  bf16x8 aF[MR / 2][2], bF[NR][2];

#define MMA_QUAD(MH, NH)                                                        \
  _Pragma("unroll") for (int mi = 0; mi < MR / 2; ++mi) {                       \
    _Pragma("unroll") for (int ni = 0; ni < NR / 2; ++ni) {                     \
      _Pragma("unroll") for (int s = 0; s < 2; ++s) {                           \
        acc[(MH) * (MR / 2) + mi][(NH) * (NR / 2) + ni] =                       \
            __builtin_amdgcn_mfma_f32_16x16x32_bf16(                            \
                aF[mi][s], bF[(NH) * (NR / 2) + ni][s],                         \
                acc[(MH) * (MR / 2) + mi][(NH) * (NR / 2) + ni], 0, 0, 0);      \
      }                                                                         \
    }                                                                           \
  }

  // prologue: deadline-ordered stage of tile 0; drain only what ph0 reads
  stageA(0, 0); stageA(1, 0); stageB(0, 0); stageB(1, 0);
  if constexpr (SB == 4) { stageB(2, 0); stageB(3, 0); }
  stageA(2, 0); stageA(3, 0);
  if constexpr (SB == 4) vwait<4>(); else vwait<3>();
  BARR;

  for (int t = 0; t < NT; ++t) {
    cur = t & 1;
    const bool nx = (t + 1) < NT;
    // ---- ph0: read aF-h0 + bF-h0; issue A0,A1(t+1); wait covers bF-h1 ----
#pragma unroll
    for (int mi = 0; mi < MR / 2; ++mi)
#pragma unroll
      for (int s = 0; s < 2; ++s) aF[mi][s] = readA(mi, s);
#pragma unroll
    for (int ni = 0; ni < NR / 2; ++ni)
#pragma unroll
      for (int s = 0; s < 2; ++s) bF[ni][s] = readB(ni, s);
    if (nx) { stageA(0, t + 1); stageA(1, t + 1); }
    BARR;
    __builtin_amdgcn_s_setprio(1);
    MMA_QUAD(0, 0);
    __builtin_amdgcn_s_setprio(0);
    if (nx) vwait<4>(); else vwait<2>();
    BARR;
    // ---- ph1: read bF-h1; issue B0,B1(t+1); wait covers aF-h1 ----
#pragma unroll
    for (int ni = 0; ni < NR / 2; ++ni)
#pragma unroll
      for (int s = 0; s < 2; ++s) bF[NR / 2 + ni][s] = readB(NR / 2 + ni, s);
    if (nx) { stageB(0, t + 1); stageB(1, t + 1); }
    BARR;
    __builtin_amdgcn_s_setprio(1);
    MMA_QUAD(0, 1);
    __builtin_amdgcn_s_setprio(0);
    if (nx) vwait<4>(); else vwait<0>();
    BARR;
    // ---- ph2: read aF-h1; issue B2,B3|A2 (t+1); no wait ----
#pragma unroll
    for (int mi = 0; mi < MR / 2; ++mi)
#pragma unroll
      for (int s = 0; s < 2; ++s) aF[mi][s] = readA(MR / 2 + mi, s);
    if (nx) {
      if constexpr (SB == 4) { stageB(2, t + 1); stageB(3, t + 1); }
      else { stageA(2, t + 1); }
    }
    BARR;
    __builtin_amdgcn_s_setprio(1);
    MMA_QUAD(1, 1);
    __builtin_amdgcn_s_setprio(0);
    BARR;
    // ---- ph3: no reads; issue A2,A3|A3 (t+1); wait covers next ph0 ----
    if (nx) {
      if constexpr (SB == 4) { stageA(2, t + 1); stageA(3, t + 1); }
      else { stageA(3, t + 1); }
    }
    __builtin_amdgcn_s_setprio(1);
    MMA_QUAD(1, 0);
    __builtin_amdgcn_s_setprio(0);
    if (nx) { if constexpr (SB == 4) vwait<4>(); else vwait<3>(); }
    BARR;
  }
#undef MMA_QUAD

  // epilogue: row = t0 + wr*TM + mi*16 + (lane>>4)*4 + r ; col = n0 + wc*TN + ni*16 + (lane&15)
#pragma unroll
  for (int mi = 0; mi < MR; ++mi) {
#pragma unroll
    for (int ni = 0; ni < NR; ++ni) {
      const int col = n0 + wc * TN + ni * 16 + (lane & 15);
      float bv = 0.f;
      if constexpr (KIND == 1 || KIND == 2 || KIND == 3) bv = bias[col];
#pragma unroll
      for (int r = 0; r < 4; ++r) {
        const int row = t0 + wr * TM + mi * 16 + ((lane >> 4) << 2) + r;
        float v = acc[mi][ni][r];
        if constexpr (KIND == 0) {
          if (n0 < IDIM) {
            int b = row >> 12, pos = row & 4095;
            hpad_out[((size_t)b * PADL + 3 + pos) * IDIM + col] = (bf16_t)v;
          } else {
            gate_out[(size_t)row * IDIM + (col - IDIM)] = (bf16_t)silu_f(v);
          }
        } else if constexpr (KIND == 1) {
          float gt = (float)extra[(size_t)row * IDIM + col];
          ((bf16_t*)outp)[(size_t)row * N + col] = (bf16_t)((v + bv) * gt);
        } else if constexpr (KIND == 2) {
          ((bf16_t*)outp)[(size_t)row * N + col] = (bf16_t)silu_f(v + bv);
        } else if constexpr (KIND == 3) {
          float res = (float)extra[(size_t)row * N + col];
          ((bf16_t*)outp)[(size_t)row * N + col] = (bf16_t)(v + bv + res);
        } else {
          ((float*)outp)[(size_t)row * N + col] = v;
        }
      }
    }
  }
}

// ---------------- launch ----------------
extern "C" void kernel_launch(void* const* d_in, const int* in_sizes, int n_in,
                              void* d_out, int out_size, void* d_ws, size_t ws_size,
                              hipStream_t stream) {
  const float* hs       = (const float*)d_in[0];
  const float* in_projw = (const float*)d_in[1];
  const float* conv_w   = (const float*)d_in[2];
  const float* conv_b   = (const float*)d_in[3];
  const float* ln_g     = (const float*)d_in[4];
  const float* ln_b     = (const float*)d_in[5];
  const float* fc_w     = (const float*)d_in[6];
  const float* fc_b     = (const float*)d_in[7];
  const float* cproj_w  = (const float*)d_in[8];
  const float* cproj_b  = (const float*)d_in[9];
  const float* out_w    = (const float*)d_in[10];

  char* ws = (char*)d_ws;
  size_t off = 0;
  auto alloc = [&](size_t bytes) {
    char* p = ws + off;
    off += (bytes + 255) & ~(size_t)255;
    return p;
  };
  bf16_t* hs_b  = (bf16_t*)alloc((size_t)TOKENS * HDIM * 2);
  bf16_t* w_ip  = (bf16_t*)alloc((size_t)2 * IDIM * HDIM * 2);
  bf16_t* w2c   = (bf16_t*)alloc((size_t)IDIM * 1024 * 2);
  bf16_t* w_fc  = (bf16_t*)alloc((size_t)HDIM * IDIM * 2);
  bf16_t* w_cp  = (bf16_t*)alloc((size_t)IDIM * HDIM * 2);
  bf16_t* w_out = (bf16_t*)alloc((size_t)HDIM * IDIM * 2);
  bf16_t* hpad  = (bf16_t*)alloc((size_t)2 * PADL * IDIM * 2);
  bf16_t* gate  = (bf16_t*)alloc((size_t)TOKENS * IDIM * 2);
  bf16_t* xres  = (bf16_t*)alloc((size_t)TOKENS * IDIM * 2);

  bf16_t* t_buf = hs_b;   // reuse
  bf16_t* hn    = gate;   // reuse
  bf16_t* h2    = hpad;   // reuse

  cvt_f32_bf16<<<8192, 256, 0, stream>>>(hs, hs_b, TOKENS * HDIM / 4);
  cvt_weights<<<10240, 256, 0, stream>>>(in_projw, fc_w, cproj_w, out_w,
                                         w_ip, w_fc, w_cp, w_out);
  expand_convw<<<8192, 256, 0, stream>>>(conv_w, w2c);
  zero_pad_rows<<<48, 256, 0, stream>>>(hpad);

  // GEMM1: 256^2 tiles, grid 32*16=512 (2 rounds)
  gemm_k<0, 4096, 1024, 256, 256, 2, 4><<<512, 512, 0, stream>>>(
      hs_b, w_ip, nullptr, nullptr, nullptr, hpad, gate);
  // CONV: grid 32*8=256 (1 round)
  gemm_k<1, 2048, 1024, 256, 256, 2, 4><<<256, 512, 0, stream>>>(
      hpad, w2c, conv_b, gate, xres, nullptr, nullptr);
  ln_k<<<TOKENS, 256, 0, stream>>>(xres, ln_g, ln_b, hn);
  // GEMM2: 256x128 tiles (N=1024), grid 32*8=256 (1 round)
  gemm_k<2, 1024, 2048, 256, 128, 2, 4><<<256, 512, 0, stream>>>(
      hn, w_fc, fc_b, nullptr, t_buf, nullptr, nullptr);
  // GEMM3: grid 256
  gemm_k<3, 2048, 1024, 256, 256, 2, 4><<<256, 512, 0, stream>>>(
      t_buf, w_cp, cproj_b, xres, h2, nullptr, nullptr);
  // GEMM4: 256x128 tiles, grid 256
  gemm_k<4, 1024, 2048, 256, 128, 2, 4><<<256, 512, 0, stream>>>(
      h2, w_out, nullptr, nullptr, d_out, nullptr, nullptr);
}